// Round 21
// baseline (155.777 us; speedup 1.0000x reference)
//
#include <hip/hip_runtime.h>
#include <math.h>

#define VN 16
#define TN 2048
#define NROWS (VN*TN)   // 32768
#define DIN 64
#define HID 128
#define DKD 48
#define KNB 33
#define BR64 64
#define XPAD 68   // s_x row: 64+4 floats
#define HPAD 66   // s_h row: 64+2 floats
#define SPAD 52   // K/V/Q/R row pad (floats)
#define RQW 528   // 16*33 rq floats per t

// ---------------- Threefry-2x32, key = (0, 42) ----------------
__device__ __forceinline__ unsigned rotl32(unsigned x, int d){ return (x<<d)|(x>>(32-d)); }

__device__ __forceinline__ void tf2x32(unsigned c0, unsigned c1, unsigned& y0, unsigned& y1){
  const unsigned k0 = 0u, k1 = 42u;
  const unsigned k2 = k0 ^ k1 ^ 0x1BD11BDAu;
  unsigned x0 = c0, x1 = c1;
  x0 += k0; x1 += k1;
#define TF_R(r) { x0 += x1; x1 = rotl32(x1,(r)); x1 ^= x0; }
  TF_R(13) TF_R(15) TF_R(26) TF_R(6)   x0 += k1; x1 += k2 + 1u;
  TF_R(17) TF_R(29) TF_R(16) TF_R(24)  x0 += k2; x1 += k0 + 2u;
  TF_R(13) TF_R(15) TF_R(26) TF_R(6)   x0 += k0; x1 += k1 + 3u;
  TF_R(17) TF_R(29) TF_R(16) TF_R(24)  x0 += k1; x1 += k2 + 4u;
  TF_R(13) TF_R(15) TF_R(26) TF_R(6)   x0 += k2; x1 += k0 + 5u;
#undef TF_R
  y0 = x0; y1 = x1;
}

// exact f64 md for element n (partitionable 64-bit threefry stream, np-ref semantics)
__device__ __forceinline__ double md64_of(const float* __restrict__ max_depth, int n){
  unsigned y0, y1;
  tf2x32(0u, (unsigned)n, y0, y1);
  unsigned long long bits = (((unsigned long long)y0) << 32) | (unsigned long long)y1;
  unsigned long long fb = (bits >> 12) | 0x3FF0000000000000ull;   // [1,2)
  double f; __builtin_memcpy(&f, &fb, 8);
  f -= 1.0;
  return (double)max_depth[n] + f * (1.0/8192.0);
}

// ---------------- prep: md64 + metadata transposes [V][T] -> [T][16] ----------------
__global__ __launch_bounds__(256) void prep_kernel(const float* __restrict__ max_depth,
    const int* __restrict__ pv, const int* __restrict__ nv,
    const float* __restrict__ pm, const float* __restrict__ nm,
    const int* __restrict__ wi, const float* __restrict__ wm,
    double* __restrict__ mdT, int* __restrict__ pvT, int* __restrict__ nvT,
    float* __restrict__ pmT, float* __restrict__ nmT,
    int* __restrict__ wiT, float* __restrict__ wmT)
{
  int n = blockIdx.x*256 + threadIdx.x;
  int v = n >> 11, t = n & 2047;
  int o = t*VN + v;
  mdT[o]  = md64_of(max_depth, n);
  pvT[o]  = pv[n];
  nvT[o]  = nv[n];
  pmT[o]  = pm[n];
  nmT[o]  = nm[n];
  wiT[o]  = wi[n];
  wmT[o]  = wm[n];
}

// ---------------- rq: rqT[t][v][j] = dot(q[v*TN+t], role(v,j)) ----------------
__global__ __launch_bounds__(256) void rq_kernel(const float* __restrict__ q,
    const float* __restrict__ role_emb, float* __restrict__ rqT)
{
  __shared__ __align__(16) float s_R[KNB][SPAD];   // 6.9 KB
  __shared__ __align__(16) float s_Q[64][SPAD];    // 13.3 KB
  int tid = threadIdx.x;
  int v  = blockIdx.x >> 5;      // 16
  int tc = blockIdx.x & 31;      // 32 chunks of 64 t
  int t0 = tc*64;

  for (int idx = tid; idx < KNB*DKD; idx += 256){
    int j = idx / DKD, d = idx - j*DKD;
    int role = (j<16) ? (v*16+j) : ((j<32) ? 256+v*16+(j-16) : 512+v);
    s_R[j][d] = role_emb[(size_t)role*DKD + d];
  }
  for (int idx = tid; idx < 64*DKD; idx += 256){
    int r = idx / DKD, d = idx - r*DKD;
    s_Q[r][d] = q[((size_t)v*TN + t0 + r)*DKD + d];
  }
  __syncthreads();

  int r = tid & 63, p = tid >> 6;   // 4 j-phases
  int t = t0 + r;
  for (int j = p; j < KNB; j += 4){
    float acc = 0.0f;
    #pragma unroll
    for (int d4=0; d4<12; d4++){
      const float4 qq = *reinterpret_cast<const float4*>(&s_Q[r][4*d4]);
      const float4 rr = *reinterpret_cast<const float4*>(&s_R[j][4*d4]);
      acc = fmaf(qq.x, rr.x, acc);
      acc = fmaf(qq.y, rr.y, acc);
      acc = fmaf(qq.z, rr.z, acc);
      acc = fmaf(qq.w, rr.w, acc);
    }
    rqT[(size_t)t*RQW + v*KNB + j] = acc;
  }
}

// ---------------- q/k/v MLPs: BR=64, 8x4 tile, phased layer2 (s_h halved: 34.3 KB LDS) ----------------
__global__ __launch_bounds__(256) void qkv_kernel(const float* __restrict__ enc,
    const float* __restrict__ Wq1, const float* __restrict__ bq1,
    const float* __restrict__ Wq2, const float* __restrict__ bq2,
    const float* __restrict__ Wk1, const float* __restrict__ bk1,
    const float* __restrict__ Wk2, const float* __restrict__ bk2,
    const float* __restrict__ Wv1, const float* __restrict__ bv1,
    const float* __restrict__ Wv2, const float* __restrict__ bv2,
    float* __restrict__ qo, float* __restrict__ ko, float* __restrict__ vo)
{
  __shared__ __align__(16) float s_x[DIN][XPAD];     // 17.4 KB
  __shared__ __align__(16) float s_h[64][HPAD];      // 16.9 KB (half of H, reused)
  int tid = threadIdx.x;
  int mm   = blockIdx.x / 512;
  int base = (blockIdx.x - mm*512) * BR64;

  const float *W1, *b1, *W2, *b2; float* outp;
  if (mm == 0){ W1=Wq1; b1=bq1; W2=Wq2; b2=bq2; outp=qo; }
  else if (mm == 1){ W1=Wk1; b1=bk1; W2=Wk2; b2=bk2; outp=ko; }
  else        { W1=Wv1; b1=bv1; W2=Wv2; b2=bv2; outp=vo; }

  for (int idx = tid; idx < BR64*DIN; idx += 256){
    int r = idx >> 6, c = idx & 63;
    s_x[c][r] = enc[(size_t)(base+r)*DIN + c];
  }
  __syncthreads();

  // layer 1: 8 rows x 4 units per thread (kept in registers through phase A)
  const int u0 = (tid & 31) * 4;
  const int r0 = (tid >> 5) * 8;
  float acc[8][4];
  {
    float c0=b1[u0], c1=b1[u0+1], c2=b1[u0+2], c3=b1[u0+3];
    #pragma unroll
    for (int r=0;r<8;r++){ acc[r][0]=c0; acc[r][1]=c1; acc[r][2]=c2; acc[r][3]=c3; }
    #pragma unroll 8
    for (int i=0;i<DIN;i++){
      const float4 xa = *reinterpret_cast<const float4*>(&s_x[i][r0]);
      const float4 xb = *reinterpret_cast<const float4*>(&s_x[i][r0+4]);
      const float4 wv = *reinterpret_cast<const float4*>(&W1[i*HID + u0]);
      float xd[8] = {xa.x, xa.y, xa.z, xa.w, xb.x, xb.y, xb.z, xb.w};
      float wd[4] = {wv.x, wv.y, wv.z, wv.w};
      #pragma unroll
      for (int r=0;r<8;r++)
        #pragma unroll
        for (int j=0;j<4;j++)
          acc[r][j] = fmaf(xd[r], wd[j], acc[r][j]);
    }
  }
  // phase A: threads owning units 0..63 store their relu'd tile
  if (u0 < 64){
    #pragma unroll
    for (int j=0;j<4;j++){
      float4 h0, h1;
      h0.x=fmaxf(acc[0][j],0.0f); h0.y=fmaxf(acc[1][j],0.0f);
      h0.z=fmaxf(acc[2][j],0.0f); h0.w=fmaxf(acc[3][j],0.0f);
      h1.x=fmaxf(acc[4][j],0.0f); h1.y=fmaxf(acc[5][j],0.0f);
      h1.z=fmaxf(acc[6][j],0.0f); h1.w=fmaxf(acc[7][j],0.0f);
      *reinterpret_cast<float4*>(&s_h[u0+j][r0])   = h0;
      *reinterpret_cast<float4*>(&s_h[u0+j][r0+4]) = h1;
    }
  }
  __syncthreads();

  // layer 2: 4 rows x 3 outputs per thread; partial over i = 0..63
  const int uo0 = (tid & 15) * 3;
  const int rr0 = (tid >> 4) * 4;
  float a[4][3];
  {
    float c0=b2[uo0], c1=b2[uo0+1], c2=b2[uo0+2];
    #pragma unroll
    for (int r=0;r<4;r++){ a[r][0]=c0; a[r][1]=c1; a[r][2]=c2; }
    #pragma unroll 8
    for (int i=0;i<64;i++){
      const float4 hv = *reinterpret_cast<const float4*>(&s_h[i][rr0]);
      float w0 = W2[i*DKD+uo0], w1 = W2[i*DKD+uo0+1], w2 = W2[i*DKD+uo0+2];
      float hd[4] = {hv.x, hv.y, hv.z, hv.w};
      #pragma unroll
      for (int r=0;r<4;r++){
        a[r][0]=fmaf(hd[r],w0,a[r][0]);
        a[r][1]=fmaf(hd[r],w1,a[r][1]);
        a[r][2]=fmaf(hd[r],w2,a[r][2]);
      }
    }
  }
  __syncthreads();
  // phase B: threads owning units 64..127 store into the same buffer
  if (u0 >= 64){
    #pragma unroll
    for (int j=0;j<4;j++){
      float4 h0, h1;
      h0.x=fmaxf(acc[0][j],0.0f); h0.y=fmaxf(acc[1][j],0.0f);
      h0.z=fmaxf(acc[2][j],0.0f); h0.w=fmaxf(acc[3][j],0.0f);
      h1.x=fmaxf(acc[4][j],0.0f); h1.y=fmaxf(acc[5][j],0.0f);
      h1.z=fmaxf(acc[6][j],0.0f); h1.w=fmaxf(acc[7][j],0.0f);
      *reinterpret_cast<float4*>(&s_h[u0-64+j][r0])   = h0;
      *reinterpret_cast<float4*>(&s_h[u0-64+j][r0+4]) = h1;
    }
  }
  __syncthreads();

  // layer 2 rest: i = 64..127 (ascending order preserved -> bit-identical)
  {
    #pragma unroll 8
    for (int i=64;i<HID;i++){
      const float4 hv = *reinterpret_cast<const float4*>(&s_h[i-64][rr0]);
      float w0 = W2[i*DKD+uo0], w1 = W2[i*DKD+uo0+1], w2 = W2[i*DKD+uo0+2];
      float hd[4] = {hv.x, hv.y, hv.z, hv.w};
      #pragma unroll
      for (int r=0;r<4;r++){
        a[r][0]=fmaf(hd[r],w0,a[r][0]);
        a[r][1]=fmaf(hd[r],w1,a[r][1]);
        a[r][2]=fmaf(hd[r],w2,a[r][2]);
      }
    }
    #pragma unroll
    for (int r=0;r<4;r++){
      float* op = outp + (size_t)(base+rr0+r)*DKD;
      op[uo0]=a[r][0]; op[uo0+1]=a[r][1]; op[uo0+2]=a[r][2];
    }
  }
}

// ---------------- attention: t-major block (16 queries, 64 shared K/V slots) ----------------
__global__ __launch_bounds__(256) void attn_kernel(const float* __restrict__ qv,
    const float* __restrict__ kv, const float* __restrict__ vv,
    const double* __restrict__ mdT,
    const int* __restrict__ pvT, const int* __restrict__ nvT,
    const float* __restrict__ pmT, const float* __restrict__ nmT,
    const int* __restrict__ wiT, const float* __restrict__ wmT,
    const float* __restrict__ rqT,
    float* __restrict__ ctx_out)
{
  __shared__ __align__(16) float s_K[64][SPAD];    // 13.3 KB
  __shared__ __align__(16) float s_V[64][SPAD];    // 13.3 KB
  __shared__ __align__(16) float s_Q[16][SPAD];    // 3.3 KB
  __shared__ float s_rq[16][34];
  __shared__ int    s_g[64];
  __shared__ double s_md[16];
  __shared__ float  s_pm[16], s_nm[16], s_wm[16];
  __shared__ float  s_P1[16][17], s_P2i[16][17], s_P2n[16][17], s_pw[16];

  int tid = threadIdx.x;
  int t = blockIdx.x;
  int mbase = t*VN;

  if (tid < 64){
    int c = tid & 15, g;
    if (tid < 16)      g = pvT[mbase + c];
    else if (tid < 32) g = c*TN + t;          // indices input == flat identity
    else if (tid < 48) g = nvT[mbase + c];
    else               g = wiT[mbase + c];
    s_g[tid] = g;
  } else if (tid < 80){
    s_md[tid-64] = mdT[mbase + (tid-64)];
  } else if (tid < 96){
    s_pm[tid-80] = pmT[mbase + (tid-80)];
  } else if (tid < 112){
    s_nm[tid-96] = nmT[mbase + (tid-96)];
  } else if (tid < 128){
    s_wm[tid-112] = wmT[mbase + (tid-112)];
  }
  for (int idx = tid; idx < 16*DKD; idx += 256){
    int v = idx / DKD, d = idx - v*DKD;
    s_Q[v][d] = qv[((size_t)v*TN + t)*DKD + d];
  }
  for (int idx = tid; idx < RQW; idx += 256){
    int v = idx / KNB, j = idx - v*KNB;
    s_rq[v][j] = rqT[(size_t)t*RQW + idx];
  }
  __syncthreads();
  for (int idx = tid; idx < 64*DKD; idx += 256){
    int slot = idx / DKD, d = idx - slot*DKD;
    size_t off = (size_t)s_g[slot]*DKD + d;
    s_K[slot][d] = kv[off];
    s_V[slot][d] = vv[off];
  }
  __syncthreads();

  // ---- scores: thread (v, j), 3 shared dots + window on j==0 ----
  const int v = tid >> 4, j = tid & 15;
  float a1=0.f, a2=0.f, a3=0.f;
  #pragma unroll
  for (int d4=0; d4<12; d4++){
    const float4 qq = *reinterpret_cast<const float4*>(&s_Q[v][4*d4]);
    const float4 kp = *reinterpret_cast<const float4*>(&s_K[j][4*d4]);
    const float4 ki = *reinterpret_cast<const float4*>(&s_K[16+j][4*d4]);
    const float4 kn = *reinterpret_cast<const float4*>(&s_K[32+j][4*d4]);
    a1=fmaf(qq.x,kp.x,a1); a1=fmaf(qq.y,kp.y,a1); a1=fmaf(qq.z,kp.z,a1); a1=fmaf(qq.w,kp.w,a1);
    a2=fmaf(qq.x,ki.x,a2); a2=fmaf(qq.y,ki.y,a2); a2=fmaf(qq.z,ki.z,a2); a2=fmaf(qq.w,ki.w,a2);
    a3=fmaf(qq.x,kn.x,a3); a3=fmaf(qq.y,kn.y,a3); a3=fmaf(qq.z,kn.z,a3); a3=fmaf(qq.w,kn.w,a3);
  }
  float aw = 0.f;
  if (j == 0){
    #pragma unroll
    for (int d4=0; d4<12; d4++){
      const float4 qq = *reinterpret_cast<const float4*>(&s_Q[v][4*d4]);
      const float4 kw = *reinterpret_cast<const float4*>(&s_K[48+v][4*d4]);
      aw=fmaf(qq.x,kw.x,aw); aw=fmaf(qq.y,kw.y,aw); aw=fmaf(qq.z,kw.z,aw); aw=fmaf(qq.w,kw.w,aw);
    }
  }
  const bool comp = s_md[v] > s_md[j];     // exact f64 (np-ref semantics)
  float scP = (a1 + s_rq[v][j]) / 6.928203230275509f;
  if (s_pm[j] != 0.0f) scP = -1e9f;
  float scN = ((comp ? a2 : a3) + s_rq[v][16+j]) / 6.928203230275509f;
  if (!(comp || s_nm[j] == 0.0f)) scN = -1e9f;
  float scW = -1e9f;
  if (j == 0){
    scW = (aw + s_rq[v][32]) / 6.928203230275509f;
    if (s_wm[v] != 0.0f) scW = -1e9f;
  }
  float m = fmaxf(scP, scN);
  if (j == 0) m = fmaxf(m, scW);
  #pragma unroll
  for (int o=1;o<=8;o<<=1) m = fmaxf(m, __shfl_xor(m, o, 64));
  float eP = expf(scP - m), eN = expf(scN - m);
  float eW = (j == 0) ? expf(scW - m) : 0.0f;
  float S = eP + eN + eW;
  #pragma unroll
  for (int o=1;o<=8;o<<=1) S += __shfl_xor(S, o, 64);
  s_P1 [v][j] = eP / S;
  s_P2i[v][j] = comp ? (eN / S) : 0.0f;
  s_P2n[v][j] = comp ? 0.0f : (eN / S);
  if (j == 0) s_pw[v] = eW / S;
  __syncthreads();

  // ---- PV: thread (v, d4) for tid<192 ----
  if (tid < 192){
    int pvr = tid / 12, d4 = tid % 12;
    float4 c; c.x=0.f; c.y=0.f; c.z=0.f; c.w=0.f;
    #pragma unroll 4
    for (int jj=0; jj<16; jj++){
      float p = s_P1[pvr][jj];
      const float4 vp = *reinterpret_cast<const float4*>(&s_V[jj][4*d4]);
      c.x=fmaf(p,vp.x,c.x); c.y=fmaf(p,vp.y,c.y); c.z=fmaf(p,vp.z,c.z); c.w=fmaf(p,vp.w,c.w);
    }
    #pragma unroll 4
    for (int jj=0; jj<16; jj++){
      float pi = s_P2i[pvr][jj], pn = s_P2n[pvr][jj];
      const float4 vi = *reinterpret_cast<const float4*>(&s_V[16+jj][4*d4]);
      const float4 vn = *reinterpret_cast<const float4*>(&s_V[32+jj][4*d4]);
      c.x=fmaf(pi,vi.x,c.x); c.y=fmaf(pi,vi.y,c.y); c.z=fmaf(pi,vi.z,c.z); c.w=fmaf(pi,vi.w,c.w);
      c.x=fmaf(pn,vn.x,c.x); c.y=fmaf(pn,vn.y,c.y); c.z=fmaf(pn,vn.z,c.z); c.w=fmaf(pn,vn.w,c.w);
    }
    {
      float p = s_pw[pvr];
      const float4 vw = *reinterpret_cast<const float4*>(&s_V[48+pvr][4*d4]);
      c.x=fmaf(p,vw.x,c.x); c.y=fmaf(p,vw.y,c.y); c.z=fmaf(p,vw.z,c.z); c.w=fmaf(p,vw.w,c.w);
    }
    *reinterpret_cast<float4*>(&ctx_out[((size_t)pvr*TN + t)*DKD + 4*d4]) = c;
  }
}

// ---------------- heads: dp/mp grid-split, BR=64, 8-row x 4-unit tile ----------------
__global__ __launch_bounds__(256) void head_kernel(const float* __restrict__ enc,
    const float* __restrict__ ctx,
    const float* __restrict__ Wd1, const float* __restrict__ bd1,
    const float* __restrict__ Wd2, const float* __restrict__ bd2,
    const float* __restrict__ Wm1, const float* __restrict__ bm1,
    const float* __restrict__ Wm2, const float* __restrict__ bm2,
    float* __restrict__ dpo, float* __restrict__ mpo)
{
  __shared__ __align__(16) float s_x[DIN+DKD][XPAD];   // 29.8 KB (mp uses first 64 rows)
  int tid = threadIdx.x;     // 256
  int mode = blockIdx.x >> 9;                 // 0: dp, 1: mp
  int base = (blockIdx.x & 511) * BR64;

  const float *W1, *b1, *W2, *b2; float* outp; int nin;
  if (mode == 0){ W1=Wd1; b1=bd1; W2=Wd2; b2=bd2; outp=dpo; nin=DIN+DKD; }
  else          { W1=Wm1; b1=bm1; W2=Wm2; b2=bm2; outp=mpo; nin=DIN; }

  for (int idx = tid; idx < BR64*DIN; idx += 256){
    int r = idx >> 6, c = idx & 63;
    s_x[c][r] = enc[(size_t)(base+r)*DIN + c];
  }
  if (mode == 0){
    for (int idx = tid; idx < BR64*DKD; idx += 256){
      int r = idx / DKD, c = idx - r*DKD;
      s_x[DIN + c][r] = ctx[(size_t)(base+r)*DKD + c];
    }
  }
  __syncthreads();

  const int u0 = (tid & 31) * 4;    // 4 hidden units
  const int r0 = (tid >> 5) * 8;    // 8 rows

  float pp[8][2] = {{0,0},{0,0},{0,0},{0,0},{0,0},{0,0},{0,0},{0,0}};
  {
    float acc[8][4];
    float c0=b1[u0], c1=b1[u0+1], c2=b1[u0+2], c3=b1[u0+3];
    #pragma unroll
    for (int r=0;r<8;r++){ acc[r][0]=c0; acc[r][1]=c1; acc[r][2]=c2; acc[r][3]=c3; }
    #pragma unroll 8
    for (int i=0;i<nin;i++){
      const float4 xa = *reinterpret_cast<const float4*>(&s_x[i][r0]);
      const float4 xb = *reinterpret_cast<const float4*>(&s_x[i][r0+4]);
      const float4 wv = *reinterpret_cast<const float4*>(&W1[i*HID + u0]);
      float xd[8] = {xa.x, xa.y, xa.z, xa.w, xb.x, xb.y, xb.z, xb.w};
      float wd[4] = {wv.x, wv.y, wv.z, wv.w};
      #pragma unroll
      for (int r=0;r<8;r++)
        #pragma unroll
        for (int j=0;j<4;j++)
          acc[r][j] = fmaf(xd[r], wd[j], acc[r][j]);
    }
    #pragma unroll
    for (int j=0;j<4;j++){
      const float2 w2 = *reinterpret_cast<const float2*>(&W2[(u0+j)*2]);
      #pragma unroll
      for (int r=0;r<8;r++){
        float h = fmaxf(acc[r][j], 0.0f);
        pp[r][0] = fmaf(h, w2.x, pp[r][0]);
        pp[r][1] = fmaf(h, w2.y, pp[r][1]);
      }
    }
  }
  // tree-reduce partials over the 32 lanes sharing rows r0..r0+7
  #pragma unroll
  for (int o=1;o<=16;o<<=1){
    #pragma unroll
    for (int r=0;r<8;r++){
      pp[r][0]+=__shfl_xor(pp[r][0],o,64);
      pp[r][1]+=__shfl_xor(pp[r][1],o,64);
    }
  }
  if ((tid & 31) == 0){
    float b20 = b2[0], b21 = b2[1];
    #pragma unroll
    for (int r=0;r<8;r++){
      outp[(size_t)(base+r0+r)*2    ] = pp[r][0] + b20;
      outp[(size_t)(base+r0+r)*2 + 1] = pp[r][1] + b21;
    }
  }
}

// ---------------- NLL combine ----------------
__device__ __forceinline__ double nlogp_d(double x, double mu, double ls){
  double sp = fmax(ls, 0.0) + log1p(exp(-fabs(ls)));
  double s = sp + 1e-3;
  double z = (x - mu) / s;
  return 0.5*z*z + log(s) + 0.9189385332046727417803297; // 0.5*log(2*pi)
}

__global__ __launch_bounds__(256) void nll_kernel(const float* __restrict__ uu,
    const float* __restrict__ dpo, const float* __restrict__ mpo, float* __restrict__ out)
{
  int n = blockIdx.x*256 + threadIdx.x;
  double x = (double)uu[n];
  out[n] = (float)(nlogp_d(x, (double)dpo[2*n], (double)dpo[2*n+1]) +
                   nlogp_d(x, (double)mpo[2*n], (double)mpo[2*n+1]));
}

extern "C" void kernel_launch(void* const* d_in, const int* in_sizes, int n_in,
                              void* d_out, int out_size, void* d_ws, size_t ws_size,
                              hipStream_t stream) {
  const float* encoded = (const float*)d_in[0];
  const float* u       = (const float*)d_in[1];
  const float* Wq1 = (const float*)d_in[2];  const float* bq1 = (const float*)d_in[3];
  const float* Wq2 = (const float*)d_in[4];  const float* bq2 = (const float*)d_in[5];
  const float* Wk1 = (const float*)d_in[6];  const float* bk1 = (const float*)d_in[7];
  const float* Wk2 = (const float*)d_in[8];  const float* bk2 = (const float*)d_in[9];
  const float* Wv1 = (const float*)d_in[10]; const float* bv1 = (const float*)d_in[11];
  const float* Wv2 = (const float*)d_in[12]; const float* bv2 = (const float*)d_in[13];
  const float* role_emb = (const float*)d_in[14];
  const float* Wd1 = (const float*)d_in[15]; const float* bd1 = (const float*)d_in[16];
  const float* Wd2 = (const float*)d_in[17]; const float* bd2 = (const float*)d_in[18];
  const float* Wm1 = (const float*)d_in[19]; const float* bm1 = (const float*)d_in[20];
  const float* Wm2 = (const float*)d_in[21]; const float* bm2 = (const float*)d_in[22];
  const int*   prev_values    = (const int*)d_in[23];
  const int*   next_values    = (const int*)d_in[24];
  const int*   window_indices = (const int*)d_in[25];
  const float* prev_mask   = (const float*)d_in[27];
  const float* next_mask   = (const float*)d_in[28];
  const float* window_mask = (const float*)d_in[29];
  const float* max_depth   = (const float*)d_in[30];
  float* out = (float*)d_out;

  double* mdT = (double*)d_ws;                  // 32768 f64
  float* q  = (float*)(mdT + NROWS);
  float* k  = q  + (size_t)NROWS*DKD;
  float* v  = k  + (size_t)NROWS*DKD;
  float* cx = v  + (size_t)NROWS*DKD;
  int*   pvT  = (int*)(cx + (size_t)NROWS*DKD);
  int*   nvT  = pvT + NROWS;
  float* pmT  = (float*)(nvT + NROWS);
  float* nmT  = pmT + NROWS;
  int*   wiT  = (int*)(nmT + NROWS);
  float* wmT  = (float*)(wiT + NROWS);
  float* rqT  = wmT + NROWS;                    // 2048*528 floats (4.3 MB)
  float* dpo  = rqT + (size_t)TN*RQW;           // 65536 floats
  float* mpo  = dpo + 2*NROWS;                  // 65536 floats

  prep_kernel<<<NROWS/256, 256, 0, stream>>>(max_depth,
      prev_values, next_values, prev_mask, next_mask, window_indices, window_mask,
      mdT, pvT, nvT, pmT, nmT, wiT, wmT);
  qkv_kernel<<<3*(NROWS/BR64), 256, 0, stream>>>(encoded,
      Wq1,bq1,Wq2,bq2, Wk1,bk1,Wk2,bk2, Wv1,bv1,Wv2,bv2, q, k, v);
  rq_kernel<<<512, 256, 0, stream>>>(q, role_emb, rqT);
  attn_kernel<<<TN, 256, 0, stream>>>(q, k, v, mdT,
      pvT, nvT, pmT, nmT, wiT, wmT, rqT, cx);
  head_kernel<<<2*512, 256, 0, stream>>>(encoded, cx,
      Wd1,bd1,Wd2,bd2, Wm1,bm1,Wm2,bm2, dpo, mpo);
  nll_kernel<<<NROWS/256, 256, 0, stream>>>(u, dpo, mpo, out);
}

// Round 22
// 132.850 us; speedup vs baseline: 1.1726x; 1.1726x over previous
//
#include <hip/hip_runtime.h>
#include <math.h>

#define VN 16
#define TN 2048
#define NROWS (VN*TN)   // 32768
#define DIN 64
#define HID 128
#define DKD 48
#define KNB 33
#define BR64 64
#define XPAD 68   // s_x row: 64+4 floats
#define HPAD 66   // s_h row: 64+2 floats
#define SPAD 52   // K/V/Q/R row pad (floats)
#define RQW 528   // 16*33 rq floats per t

// ---------------- Threefry-2x32, key = (0, 42) ----------------
__device__ __forceinline__ unsigned rotl32(unsigned x, int d){ return (x<<d)|(x>>(32-d)); }

__device__ __forceinline__ void tf2x32(unsigned c0, unsigned c1, unsigned& y0, unsigned& y1){
  const unsigned k0 = 0u, k1 = 42u;
  const unsigned k2 = k0 ^ k1 ^ 0x1BD11BDAu;
  unsigned x0 = c0, x1 = c1;
  x0 += k0; x1 += k1;
#define TF_R(r) { x0 += x1; x1 = rotl32(x1,(r)); x1 ^= x0; }
  TF_R(13) TF_R(15) TF_R(26) TF_R(6)   x0 += k1; x1 += k2 + 1u;
  TF_R(17) TF_R(29) TF_R(16) TF_R(24)  x0 += k2; x1 += k0 + 2u;
  TF_R(13) TF_R(15) TF_R(26) TF_R(6)   x0 += k0; x1 += k1 + 3u;
  TF_R(17) TF_R(29) TF_R(16) TF_R(24)  x0 += k1; x1 += k2 + 4u;
  TF_R(13) TF_R(15) TF_R(26) TF_R(6)   x0 += k2; x1 += k0 + 5u;
#undef TF_R
  y0 = x0; y1 = x1;
}

// exact f64 md for element n (partitionable 64-bit threefry stream, np-ref semantics)
__device__ __forceinline__ double md64_of(const float* __restrict__ max_depth, int n){
  unsigned y0, y1;
  tf2x32(0u, (unsigned)n, y0, y1);
  unsigned long long bits = (((unsigned long long)y0) << 32) | (unsigned long long)y1;
  unsigned long long fb = (bits >> 12) | 0x3FF0000000000000ull;   // [1,2)
  double f; __builtin_memcpy(&f, &fb, 8);
  f -= 1.0;
  return (double)max_depth[n] + f * (1.0/8192.0);
}

// ---------------- prep: md64 + metadata transposes [V][T] -> [T][16] ----------------
__global__ __launch_bounds__(256) void prep_kernel(const float* __restrict__ max_depth,
    const int* __restrict__ pv, const int* __restrict__ nv,
    const float* __restrict__ pm, const float* __restrict__ nm,
    const int* __restrict__ wi, const float* __restrict__ wm,
    double* __restrict__ mdT, int* __restrict__ pvT, int* __restrict__ nvT,
    float* __restrict__ pmT, float* __restrict__ nmT,
    int* __restrict__ wiT, float* __restrict__ wmT)
{
  int n = blockIdx.x*256 + threadIdx.x;
  int v = n >> 11, t = n & 2047;
  int o = t*VN + v;
  mdT[o]  = md64_of(max_depth, n);
  pvT[o]  = pv[n];
  nvT[o]  = nv[n];
  pmT[o]  = pm[n];
  nmT[o]  = nm[n];
  wiT[o]  = wi[n];
  wmT[o]  = wm[n];
}

// ---------------- rq: rqT[t][v][j] = dot(q[v*TN+t], role(v,j)) ----------------
__global__ __launch_bounds__(256) void rq_kernel(const float* __restrict__ q,
    const float* __restrict__ role_emb, float* __restrict__ rqT)
{
  __shared__ __align__(16) float s_R[KNB][SPAD];   // 6.9 KB
  __shared__ __align__(16) float s_Q[64][SPAD];    // 13.3 KB
  int tid = threadIdx.x;
  int v  = blockIdx.x >> 5;      // 16
  int tc = blockIdx.x & 31;      // 32 chunks of 64 t
  int t0 = tc*64;

  for (int idx = tid; idx < KNB*DKD; idx += 256){
    int j = idx / DKD, d = idx - j*DKD;
    int role = (j<16) ? (v*16+j) : ((j<32) ? 256+v*16+(j-16) : 512+v);
    s_R[j][d] = role_emb[(size_t)role*DKD + d];
  }
  for (int idx = tid; idx < 64*DKD; idx += 256){
    int r = idx / DKD, d = idx - r*DKD;
    s_Q[r][d] = q[((size_t)v*TN + t0 + r)*DKD + d];
  }
  __syncthreads();

  int r = tid & 63, p = tid >> 6;   // 4 j-phases
  int t = t0 + r;
  for (int j = p; j < KNB; j += 4){
    float acc = 0.0f;
    #pragma unroll
    for (int d4=0; d4<12; d4++){
      const float4 qq = *reinterpret_cast<const float4*>(&s_Q[r][4*d4]);
      const float4 rr = *reinterpret_cast<const float4*>(&s_R[j][4*d4]);
      acc = fmaf(qq.x, rr.x, acc);
      acc = fmaf(qq.y, rr.y, acc);
      acc = fmaf(qq.z, rr.z, acc);
      acc = fmaf(qq.w, rr.w, acc);
    }
    rqT[(size_t)t*RQW + v*KNB + j] = acc;
  }
}

// ---------------- q/k/v MLPs: BR=64, 8-row x 4-unit tile, streamed W (R18-proven) ----------------
__global__ __launch_bounds__(256) void qkv_kernel(const float* __restrict__ enc,
    const float* __restrict__ Wq1, const float* __restrict__ bq1,
    const float* __restrict__ Wq2, const float* __restrict__ bq2,
    const float* __restrict__ Wk1, const float* __restrict__ bk1,
    const float* __restrict__ Wk2, const float* __restrict__ bk2,
    const float* __restrict__ Wv1, const float* __restrict__ bv1,
    const float* __restrict__ Wv2, const float* __restrict__ bv2,
    float* __restrict__ qo, float* __restrict__ ko, float* __restrict__ vo)
{
  __shared__ __align__(16) float s_x[DIN][XPAD];     // 17.4 KB
  __shared__ __align__(16) float s_h[HID][HPAD];     // 33.8 KB
  int tid = threadIdx.x;
  int mm   = blockIdx.x / 512;
  int base = (blockIdx.x - mm*512) * BR64;

  const float *W1, *b1, *W2, *b2; float* outp;
  if (mm == 0){ W1=Wq1; b1=bq1; W2=Wq2; b2=bq2; outp=qo; }
  else if (mm == 1){ W1=Wk1; b1=bk1; W2=Wk2; b2=bk2; outp=ko; }
  else        { W1=Wv1; b1=bv1; W2=Wv2; b2=bv2; outp=vo; }

  for (int idx = tid; idx < BR64*DIN; idx += 256){
    int r = idx >> 6, c = idx & 63;
    s_x[c][r] = enc[(size_t)(base+r)*DIN + c];
  }
  __syncthreads();

  // layer 1: 8 rows x 4 units per thread
  const int u0 = (tid & 31) * 4;
  const int r0 = (tid >> 5) * 8;
  {
    float acc[8][4];
    float c0=b1[u0], c1=b1[u0+1], c2=b1[u0+2], c3=b1[u0+3];
    #pragma unroll
    for (int r=0;r<8;r++){ acc[r][0]=c0; acc[r][1]=c1; acc[r][2]=c2; acc[r][3]=c3; }
    #pragma unroll 8
    for (int i=0;i<DIN;i++){
      const float4 xa = *reinterpret_cast<const float4*>(&s_x[i][r0]);
      const float4 xb = *reinterpret_cast<const float4*>(&s_x[i][r0+4]);
      const float4 wv = *reinterpret_cast<const float4*>(&W1[i*HID + u0]);
      float xd[8] = {xa.x, xa.y, xa.z, xa.w, xb.x, xb.y, xb.z, xb.w};
      float wd[4] = {wv.x, wv.y, wv.z, wv.w};
      #pragma unroll
      for (int r=0;r<8;r++)
        #pragma unroll
        for (int j=0;j<4;j++)
          acc[r][j] = fmaf(xd[r], wd[j], acc[r][j]);
    }
    #pragma unroll
    for (int j=0;j<4;j++){
      float4 h0, h1;
      h0.x=fmaxf(acc[0][j],0.0f); h0.y=fmaxf(acc[1][j],0.0f);
      h0.z=fmaxf(acc[2][j],0.0f); h0.w=fmaxf(acc[3][j],0.0f);
      h1.x=fmaxf(acc[4][j],0.0f); h1.y=fmaxf(acc[5][j],0.0f);
      h1.z=fmaxf(acc[6][j],0.0f); h1.w=fmaxf(acc[7][j],0.0f);
      *reinterpret_cast<float4*>(&s_h[u0+j][r0])   = h0;
      *reinterpret_cast<float4*>(&s_h[u0+j][r0+4]) = h1;
    }
  }
  __syncthreads();

  // layer 2: 4 rows x 3 outputs per thread
  const int uo0 = (tid & 15) * 3;
  const int rr0 = (tid >> 4) * 4;
  {
    float a[4][3];
    float c0=b2[uo0], c1=b2[uo0+1], c2=b2[uo0+2];
    #pragma unroll
    for (int r=0;r<4;r++){ a[r][0]=c0; a[r][1]=c1; a[r][2]=c2; }
    #pragma unroll 8
    for (int i=0;i<HID;i++){
      const float4 hv = *reinterpret_cast<const float4*>(&s_h[i][rr0]);
      float w0 = W2[i*DKD+uo0], w1 = W2[i*DKD+uo0+1], w2 = W2[i*DKD+uo0+2];
      float hd[4] = {hv.x, hv.y, hv.z, hv.w};
      #pragma unroll
      for (int r=0;r<4;r++){
        a[r][0]=fmaf(hd[r],w0,a[r][0]);
        a[r][1]=fmaf(hd[r],w1,a[r][1]);
        a[r][2]=fmaf(hd[r],w2,a[r][2]);
      }
    }
    #pragma unroll
    for (int r=0;r<4;r++){
      float* op = outp + (size_t)(base+rr0+r)*DKD;
      op[uo0]=a[r][0]; op[uo0+1]=a[r][1]; op[uo0+2]=a[r][2];
    }
  }
}

// ---------------- attention: t-major block (16 queries, 64 shared K/V slots) ----------------
__global__ __launch_bounds__(256) void attn_kernel(const float* __restrict__ qv,
    const float* __restrict__ kv, const float* __restrict__ vv,
    const double* __restrict__ mdT,
    const int* __restrict__ pvT, const int* __restrict__ nvT,
    const float* __restrict__ pmT, const float* __restrict__ nmT,
    const int* __restrict__ wiT, const float* __restrict__ wmT,
    const float* __restrict__ rqT,
    float* __restrict__ ctx_out)
{
  __shared__ __align__(16) float s_K[64][SPAD];    // 13.3 KB
  __shared__ __align__(16) float s_V[64][SPAD];    // 13.3 KB
  __shared__ __align__(16) float s_Q[16][SPAD];    // 3.3 KB
  __shared__ float s_rq[16][34];
  __shared__ int    s_g[64];
  __shared__ double s_md[16];
  __shared__ float  s_pm[16], s_nm[16], s_wm[16];
  __shared__ float  s_P1[16][17], s_P2i[16][17], s_P2n[16][17], s_pw[16];

  int tid = threadIdx.x;
  int t = blockIdx.x;
  int mbase = t*VN;

  if (tid < 64){
    int c = tid & 15, g;
    if (tid < 16)      g = pvT[mbase + c];
    else if (tid < 32) g = c*TN + t;          // indices input == flat identity
    else if (tid < 48) g = nvT[mbase + c];
    else               g = wiT[mbase + c];
    s_g[tid] = g;
  } else if (tid < 80){
    s_md[tid-64] = mdT[mbase + (tid-64)];
  } else if (tid < 96){
    s_pm[tid-80] = pmT[mbase + (tid-80)];
  } else if (tid < 112){
    s_nm[tid-96] = nmT[mbase + (tid-96)];
  } else if (tid < 128){
    s_wm[tid-112] = wmT[mbase + (tid-112)];
  }
  for (int idx = tid; idx < 16*DKD; idx += 256){
    int v = idx / DKD, d = idx - v*DKD;
    s_Q[v][d] = qv[((size_t)v*TN + t)*DKD + d];
  }
  for (int idx = tid; idx < RQW; idx += 256){
    int v = idx / KNB, j = idx - v*KNB;
    s_rq[v][j] = rqT[(size_t)t*RQW + idx];
  }
  __syncthreads();
  for (int idx = tid; idx < 64*DKD; idx += 256){
    int slot = idx / DKD, d = idx - slot*DKD;
    size_t off = (size_t)s_g[slot]*DKD + d;
    s_K[slot][d] = kv[off];
    s_V[slot][d] = vv[off];
  }
  __syncthreads();

  // ---- scores: thread (v, j), 3 shared dots + window on j==0 ----
  const int v = tid >> 4, j = tid & 15;
  float a1=0.f, a2=0.f, a3=0.f;
  #pragma unroll
  for (int d4=0; d4<12; d4++){
    const float4 qq = *reinterpret_cast<const float4*>(&s_Q[v][4*d4]);
    const float4 kp = *reinterpret_cast<const float4*>(&s_K[j][4*d4]);
    const float4 ki = *reinterpret_cast<const float4*>(&s_K[16+j][4*d4]);
    const float4 kn = *reinterpret_cast<const float4*>(&s_K[32+j][4*d4]);
    a1=fmaf(qq.x,kp.x,a1); a1=fmaf(qq.y,kp.y,a1); a1=fmaf(qq.z,kp.z,a1); a1=fmaf(qq.w,kp.w,a1);
    a2=fmaf(qq.x,ki.x,a2); a2=fmaf(qq.y,ki.y,a2); a2=fmaf(qq.z,ki.z,a2); a2=fmaf(qq.w,ki.w,a2);
    a3=fmaf(qq.x,kn.x,a3); a3=fmaf(qq.y,kn.y,a3); a3=fmaf(qq.z,kn.z,a3); a3=fmaf(qq.w,kn.w,a3);
  }
  float aw = 0.f;
  if (j == 0){
    #pragma unroll
    for (int d4=0; d4<12; d4++){
      const float4 qq = *reinterpret_cast<const float4*>(&s_Q[v][4*d4]);
      const float4 kw = *reinterpret_cast<const float4*>(&s_K[48+v][4*d4]);
      aw=fmaf(qq.x,kw.x,aw); aw=fmaf(qq.y,kw.y,aw); aw=fmaf(qq.z,kw.z,aw); aw=fmaf(qq.w,kw.w,aw);
    }
  }
  const bool comp = s_md[v] > s_md[j];     // exact f64 (np-ref semantics)
  float scP = (a1 + s_rq[v][j]) / 6.928203230275509f;
  if (s_pm[j] != 0.0f) scP = -1e9f;
  float scN = ((comp ? a2 : a3) + s_rq[v][16+j]) / 6.928203230275509f;
  if (!(comp || s_nm[j] == 0.0f)) scN = -1e9f;
  float scW = -1e9f;
  if (j == 0){
    scW = (aw + s_rq[v][32]) / 6.928203230275509f;
    if (s_wm[v] != 0.0f) scW = -1e9f;
  }
  float m = fmaxf(scP, scN);
  if (j == 0) m = fmaxf(m, scW);
  #pragma unroll
  for (int o=1;o<=8;o<<=1) m = fmaxf(m, __shfl_xor(m, o, 64));
  float eP = expf(scP - m), eN = expf(scN - m);
  float eW = (j == 0) ? expf(scW - m) : 0.0f;
  float S = eP + eN + eW;
  #pragma unroll
  for (int o=1;o<=8;o<<=1) S += __shfl_xor(S, o, 64);
  s_P1 [v][j] = eP / S;
  s_P2i[v][j] = comp ? (eN / S) : 0.0f;
  s_P2n[v][j] = comp ? 0.0f : (eN / S);
  if (j == 0) s_pw[v] = eW / S;
  __syncthreads();

  // ---- PV: thread (v, d4) for tid<192 ----
  if (tid < 192){
    int pvr = tid / 12, d4 = tid % 12;
    float4 c; c.x=0.f; c.y=0.f; c.z=0.f; c.w=0.f;
    #pragma unroll 4
    for (int jj=0; jj<16; jj++){
      float p = s_P1[pvr][jj];
      const float4 vp = *reinterpret_cast<const float4*>(&s_V[jj][4*d4]);
      c.x=fmaf(p,vp.x,c.x); c.y=fmaf(p,vp.y,c.y); c.z=fmaf(p,vp.z,c.z); c.w=fmaf(p,vp.w,c.w);
    }
    #pragma unroll 4
    for (int jj=0; jj<16; jj++){
      float pi = s_P2i[pvr][jj], pn = s_P2n[pvr][jj];
      const float4 vi = *reinterpret_cast<const float4*>(&s_V[16+jj][4*d4]);
      const float4 vn = *reinterpret_cast<const float4*>(&s_V[32+jj][4*d4]);
      c.x=fmaf(pi,vi.x,c.x); c.y=fmaf(pi,vi.y,c.y); c.z=fmaf(pi,vi.z,c.z); c.w=fmaf(pi,vi.w,c.w);
      c.x=fmaf(pn,vn.x,c.x); c.y=fmaf(pn,vn.y,c.y); c.z=fmaf(pn,vn.z,c.z); c.w=fmaf(pn,vn.w,c.w);
    }
    {
      float p = s_pw[pvr];
      const float4 vw = *reinterpret_cast<const float4*>(&s_V[48+pvr][4*d4]);
      c.x=fmaf(p,vw.x,c.x); c.y=fmaf(p,vw.y,c.y); c.z=fmaf(p,vw.z,c.z); c.w=fmaf(p,vw.w,c.w);
    }
    *reinterpret_cast<float4*>(&ctx_out[((size_t)pvr*TN + t)*DKD + 4*d4]) = c;
  }
}

// ---------------- heads: dp/mp grid-split, BR=64, 8-row x 4-unit tile ----------------
__global__ __launch_bounds__(256) void head_kernel(const float* __restrict__ enc,
    const float* __restrict__ ctx,
    const float* __restrict__ Wd1, const float* __restrict__ bd1,
    const float* __restrict__ Wd2, const float* __restrict__ bd2,
    const float* __restrict__ Wm1, const float* __restrict__ bm1,
    const float* __restrict__ Wm2, const float* __restrict__ bm2,
    float* __restrict__ dpo, float* __restrict__ mpo)
{
  __shared__ __align__(16) float s_x[DIN+DKD][XPAD];   // 29.8 KB (mp uses first 64 rows)
  int tid = threadIdx.x;     // 256
  int mode = blockIdx.x >> 9;                 // 0: dp, 1: mp
  int base = (blockIdx.x & 511) * BR64;

  const float *W1, *b1, *W2, *b2; float* outp; int nin;
  if (mode == 0){ W1=Wd1; b1=bd1; W2=Wd2; b2=bd2; outp=dpo; nin=DIN+DKD; }
  else          { W1=Wm1; b1=bm1; W2=Wm2; b2=bm2; outp=mpo; nin=DIN; }

  for (int idx = tid; idx < BR64*DIN; idx += 256){
    int r = idx >> 6, c = idx & 63;
    s_x[c][r] = enc[(size_t)(base+r)*DIN + c];
  }
  if (mode == 0){
    for (int idx = tid; idx < BR64*DKD; idx += 256){
      int r = idx / DKD, c = idx - r*DKD;
      s_x[DIN + c][r] = ctx[(size_t)(base+r)*DKD + c];
    }
  }
  __syncthreads();

  const int u0 = (tid & 31) * 4;    // 4 hidden units
  const int r0 = (tid >> 5) * 8;    // 8 rows

  float pp[8][2] = {{0,0},{0,0},{0,0},{0,0},{0,0},{0,0},{0,0},{0,0}};
  {
    float acc[8][4];
    float c0=b1[u0], c1=b1[u0+1], c2=b1[u0+2], c3=b1[u0+3];
    #pragma unroll
    for (int r=0;r<8;r++){ acc[r][0]=c0; acc[r][1]=c1; acc[r][2]=c2; acc[r][3]=c3; }
    #pragma unroll 8
    for (int i=0;i<nin;i++){
      const float4 xa = *reinterpret_cast<const float4*>(&s_x[i][r0]);
      const float4 xb = *reinterpret_cast<const float4*>(&s_x[i][r0+4]);
      const float4 wv = *reinterpret_cast<const float4*>(&W1[i*HID + u0]);
      float xd[8] = {xa.x, xa.y, xa.z, xa.w, xb.x, xb.y, xb.z, xb.w};
      float wd[4] = {wv.x, wv.y, wv.z, wv.w};
      #pragma unroll
      for (int r=0;r<8;r++)
        #pragma unroll
        for (int j=0;j<4;j++)
          acc[r][j] = fmaf(xd[r], wd[j], acc[r][j]);
    }
    #pragma unroll
    for (int j=0;j<4;j++){
      const float2 w2 = *reinterpret_cast<const float2*>(&W2[(u0+j)*2]);
      #pragma unroll
      for (int r=0;r<8;r++){
        float h = fmaxf(acc[r][j], 0.0f);
        pp[r][0] = fmaf(h, w2.x, pp[r][0]);
        pp[r][1] = fmaf(h, w2.y, pp[r][1]);
      }
    }
  }
  // tree-reduce partials over the 32 lanes sharing rows r0..r0+7
  #pragma unroll
  for (int o=1;o<=16;o<<=1){
    #pragma unroll
    for (int r=0;r<8;r++){
      pp[r][0]+=__shfl_xor(pp[r][0],o,64);
      pp[r][1]+=__shfl_xor(pp[r][1],o,64);
    }
  }
  if ((tid & 31) == 0){
    float b20 = b2[0], b21 = b2[1];
    #pragma unroll
    for (int r=0;r<8;r++){
      outp[(size_t)(base+r0+r)*2    ] = pp[r][0] + b20;
      outp[(size_t)(base+r0+r)*2 + 1] = pp[r][1] + b21;
    }
  }
}

// ---------------- NLL combine ----------------
__device__ __forceinline__ double nlogp_d(double x, double mu, double ls){
  double sp = fmax(ls, 0.0) + log1p(exp(-fabs(ls)));
  double s = sp + 1e-3;
  double z = (x - mu) / s;
  return 0.5*z*z + log(s) + 0.9189385332046727417803297; // 0.5*log(2*pi)
}

__global__ __launch_bounds__(256) void nll_kernel(const float* __restrict__ uu,
    const float* __restrict__ dpo, const float* __restrict__ mpo, float* __restrict__ out)
{
  int n = blockIdx.x*256 + threadIdx.x;
  double x = (double)uu[n];
  out[n] = (float)(nlogp_d(x, (double)dpo[2*n], (double)dpo[2*n+1]) +
                   nlogp_d(x, (double)mpo[2*n], (double)mpo[2*n+1]));
}

extern "C" void kernel_launch(void* const* d_in, const int* in_sizes, int n_in,
                              void* d_out, int out_size, void* d_ws, size_t ws_size,
                              hipStream_t stream) {
  const float* encoded = (const float*)d_in[0];
  const float* u       = (const float*)d_in[1];
  const float* Wq1 = (const float*)d_in[2];  const float* bq1 = (const float*)d_in[3];
  const float* Wq2 = (const float*)d_in[4];  const float* bq2 = (const float*)d_in[5];
  const float* Wk1 = (const float*)d_in[6];  const float* bk1 = (const float*)d_in[7];
  const float* Wk2 = (const float*)d_in[8];  const float* bk2 = (const float*)d_in[9];
  const float* Wv1 = (const float*)d_in[10]; const float* bv1 = (const float*)d_in[11];
  const float* Wv2 = (const float*)d_in[12]; const float* bv2 = (const float*)d_in[13];
  const float* role_emb = (const float*)d_in[14];
  const float* Wd1 = (const float*)d_in[15]; const float* bd1 = (const float*)d_in[16];
  const float* Wd2 = (const float*)d_in[17]; const float* bd2 = (const float*)d_in[18];
  const float* Wm1 = (const float*)d_in[19]; const float* bm1 = (const float*)d_in[20];
  const float* Wm2 = (const float*)d_in[21]; const float* bm2 = (const float*)d_in[22];
  const int*   prev_values    = (const int*)d_in[23];
  const int*   next_values    = (const int*)d_in[24];
  const int*   window_indices = (const int*)d_in[25];
  const float* prev_mask   = (const float*)d_in[27];
  const float* next_mask   = (const float*)d_in[28];
  const float* window_mask = (const float*)d_in[29];
  const float* max_depth   = (const float*)d_in[30];
  float* out = (float*)d_out;

  double* mdT = (double*)d_ws;                  // 32768 f64
  float* q  = (float*)(mdT + NROWS);
  float* k  = q  + (size_t)NROWS*DKD;
  float* v  = k  + (size_t)NROWS*DKD;
  float* cx = v  + (size_t)NROWS*DKD;
  int*   pvT  = (int*)(cx + (size_t)NROWS*DKD);
  int*   nvT  = pvT + NROWS;
  float* pmT  = (float*)(nvT + NROWS);
  float* nmT  = pmT + NROWS;
  int*   wiT  = (int*)(nmT + NROWS);
  float* wmT  = (float*)(wiT + NROWS);
  float* rqT  = wmT + NROWS;                    // 2048*528 floats (4.3 MB)
  float* dpo  = rqT + (size_t)TN*RQW;           // 65536 floats
  float* mpo  = dpo + 2*NROWS;                  // 65536 floats

  prep_kernel<<<NROWS/256, 256, 0, stream>>>(max_depth,
      prev_values, next_values, prev_mask, next_mask, window_indices, window_mask,
      mdT, pvT, nvT, pmT, nmT, wiT, wmT);
  qkv_kernel<<<3*(NROWS/BR64), 256, 0, stream>>>(encoded,
      Wq1,bq1,Wq2,bq2, Wk1,bk1,Wk2,bk2, Wv1,bv1,Wv2,bv2, q, k, v);
  rq_kernel<<<512, 256, 0, stream>>>(q, role_emb, rqT);
  attn_kernel<<<TN, 256, 0, stream>>>(q, k, v, mdT,
      pvT, nvT, pmT, nmT, wiT, wmT, rqT, cx);
  head_kernel<<<2*512, 256, 0, stream>>>(encoded, cx,
      Wd1,bd1,Wd2,bd2, Wm1,bm1,Wm2,bm2, dpo, mpo);
  nll_kernel<<<NROWS/256, 256, 0, stream>>>(u, dpo, mpo, out);
}